// Round 12
// baseline (500.016 us; speedup 1.0000x reference)
//
#include <hip/hip_runtime.h>
#include <stdint.h>

#define B_ 8
#define N_ 8192
#define DIM_ 512
#define H_ 8
#define DH_ 64
#define ROWS (B_*N_)        // 65536
#define TRIPLE (3*DIM_)     // 1536
#define EPS_ 1e-5f

typedef __attribute__((ext_vector_type(8))) short short8;
typedef __attribute__((ext_vector_type(4))) float f32x4;
typedef __attribute__((ext_vector_type(4))) float fl4;
typedef __attribute__((ext_vector_type(4))) unsigned short us4;
typedef __attribute__((ext_vector_type(8))) unsigned short us8;

#define AS1 __attribute__((address_space(1)))
#define AS3 __attribute__((address_space(3)))

__device__ __forceinline__ void gld16(const void* g, void* l) {
    // async global->LDS, 16B/lane; LDS dest = wave-uniform base + lane*16
    __builtin_amdgcn_global_load_lds((const AS1 void*)(uintptr_t)g,
                                     (AS3 void*)(unsigned)(uintptr_t)l, 16, 0, 0);
}

__device__ inline unsigned short f2bf(float f) {
    union { float f; unsigned int u; } x; x.f = f;
    unsigned int r = x.u + 0x7fffu + ((x.u >> 16) & 1u);
    return (unsigned short)(r >> 16);
}
__device__ inline float bf2f(unsigned short b) {
    union { unsigned int u; float f; } x; x.u = ((unsigned int)b) << 16;
    return x.f;
}

// epilogue LDS swizzle (k_qkv8): XOR the 32B-block index by the fragment
// row-group so the 4 row-groups of one fragment-store hit disjoint octets.
__device__ __forceinline__ int eoff(int row, int col) {
    return row * 64 + (col ^ ((((unsigned)row >> 2) & 3) << 4));
}

// attnS swizzle (k_ao): XOR the 8-ushort granule index by row&7 so the
// 16-row fragment reads (stride 1024B) spread across 8 bank-quads (2-way).
__device__ __forceinline__ int aoff(int row, int col) {
    return row * 512 + ((((col >> 3) ^ (row & 7)) << 3) | (col & 7));
}

// ---------------------------------------------------------------------------
// k_cvt: x fp32 -> bf16 (row-major unchanged), enables async A-staging in k_qkv
__global__ __launch_bounds__(256) void k_cvt(const float* __restrict__ x,
                                             unsigned short* __restrict__ xb) {
    size_t i = ((size_t)blockIdx.x * 256 + threadIdx.x) * 8;
    fl4 a = *(const fl4*)(x + i);
    fl4 b = *(const fl4*)(x + i + 4);
    us8 r;
    r[0] = f2bf(a[0]); r[1] = f2bf(a[1]); r[2] = f2bf(a[2]); r[3] = f2bf(a[3]);
    r[4] = f2bf(b[0]); r[5] = f2bf(b[1]); r[6] = f2bf(b[2]); r[7] = f2bf(b[3]);
    *(us8*)(xb + i) = r;
}

// ---------------------------------------------------------------------------
// k_prep: coalesced LDS-tiled transpose+convert of both weights to bf16 [n][k].
__global__ __launch_bounds__(256) void k_prep(const float* __restrict__ wq,
        const float* __restrict__ wo,
        unsigned short* __restrict__ wqT, unsigned short* __restrict__ woT) {
    __shared__ float T[32][33];
    int bid = blockIdx.x;
    const float* src; unsigned short* dst; int srcCols, dstCols, k0, n0;
    if (bid < 768) {                  // w_qkv: [512][1536] -> [1536][512]
        int tn = bid % 48, tk = bid / 48;
        src = wq; dst = wqT; srcCols = 1536; dstCols = 512;
        k0 = tk * 32; n0 = tn * 32;
    } else {                          // w_out: [512][512] -> [512][512]
        int b = bid - 768;
        int tn = b % 16, tk = b / 16;
        src = wo; dst = woT; srcCols = 512; dstCols = 512;
        k0 = tk * 32; n0 = tn * 32;
    }
    int t = threadIdx.x, r = t >> 3, c4 = (t & 7) * 4;
    fl4 v = *(const fl4*)(src + (size_t)(k0 + r) * srcCols + n0 + c4);
    T[c4 + 0][r] = v[0]; T[c4 + 1][r] = v[1];
    T[c4 + 2][r] = v[2]; T[c4 + 3][r] = v[3];
    __syncthreads();
    us4 o;
    o[0] = f2bf(T[r][c4 + 0]); o[1] = f2bf(T[r][c4 + 1]);
    o[2] = f2bf(T[r][c4 + 2]); o[3] = f2bf(T[r][c4 + 3]);
    *(us4*)(dst + (size_t)(n0 + r) * dstCols + k0 + c4) = o;
}

// ---------------------------------------------------------------------------
// k_qkv8: round-7..11 proven kernel, VERBATIM (256x128 tile, BK=32, ring-3,
//   depth-2, counted vmcnt(3), 2 blocks/CU).
__global__ __launch_bounds__(512, 4) void k_qkv8(const unsigned short* __restrict__ xb,
        const unsigned short* __restrict__ wT,      // [1536][512] bf16
        unsigned short* __restrict__ qkv)           // [65536][1536] bf16
{
    // slot layout: A = ushort [0, 8192) (256x32), B = [8192, 12288) (128x32)
    __shared__ __align__(1024) unsigned short LDSb[3][12288];   // 72 KB

    const int tid  = threadIdx.x;
    const int lane = tid & 63;
    const int wid  = tid >> 6;     // 0..7
    const int wr   = wid >> 1;     // 0..3  (M quarter, 64 rows)
    const int wc   = wid & 1;      // 0..1  (N half, 64 cols)
    const int lr   = lane & 15;

    // bijective XCD swizzle (3072 % 8 == 0): 12 N-blocks share an A-panel
    // within one XCD's 384-block chunk.
    int id  = blockIdx.x;
    int nid = (id & 7) * 384 + (id >> 3);
    int n0  = (nid % 12) * 128;
    int m0  = (nid / 12) * 256;

    // ---- staging source coords (inverse of st_16x32 swizzle; LDS dest linear)
    const unsigned short* pA[2];
    const unsigned short* pB1;
    unsigned ldstA[2], ldstB;
#pragma unroll
    for (int j = 0; j < 2; ++j) {
        int s    = tid + j * 512;
        int row  = ((s >> 6) << 4) + ((s >> 2) & 15);
        int colb = ((s & 3) << 4) ^ (((s >> 5) & 1) << 5);
        pA[j] = xb + (size_t)(m0 + row) * 512 + (colb >> 1);
        ldstA[j] = (unsigned)((j * 512 + wid * 64) * 8);   // ushort idx
    }
    {
        int s    = tid;
        int row  = ((s >> 6) << 4) + ((s >> 2) & 15);
        int colb = ((s & 3) << 4) ^ (((s >> 5) & 1) << 5);
        pB1 = wT + (size_t)(n0 + row) * 512 + (colb >> 1);
        ldstB = (unsigned)(8192 + wid * 64 * 8);
    }
    // swizzled ds_read lane offset (ushort idx within a subtile)
    const int kg = (lane >> 4) * 8;
    const int lo = lr * 32 + (kg ^ ((lr >> 3) << 4));

    auto STAGE = [&](int t, int slot) {
        gld16(pA[0] + t * 32, (void*)&LDSb[slot][ldstA[0]]);
        gld16(pA[1] + t * 32, (void*)&LDSb[slot][ldstA[1]]);
        gld16(pB1   + t * 32, (void*)&LDSb[slot][ldstB]);
    };

    f32x4 acc[4][4] = {};
    short8 af[4], bfr[4];

    STAGE(0, 0);
    STAGE(1, 1);

#define WAITV(n) asm volatile("s_waitcnt vmcnt(" #n ")" ::: "memory")
#pragma unroll
    for (int t = 0; t < 16; ++t) {
        // outstanding at top: tiles t (3) + t+1 (3); leave t+1's in flight.
        if (t <= 14) WAITV(3);
        else         WAITV(0);
        __builtin_amdgcn_s_barrier();          // all waves' tile-t loads landed
        __builtin_amdgcn_sched_barrier(0);     // pin: nothing hoists above

        if (t + 2 < 16) STAGE(t + 2, (t + 2) % 3);  // slot (t-1)%3: readers done

        const unsigned short* L = LDSb[t % 3];
#pragma unroll
        for (int m = 0; m < 4; ++m)
            af[m] = *(const short8*)&L[(wr * 4 + m) * 512 + lo];
#pragma unroll
        for (int n = 0; n < 4; ++n)
            bfr[n] = *(const short8*)&L[8192 + (wc * 4 + n) * 512 + lo];

        __builtin_amdgcn_s_setprio(1);
#pragma unroll
        for (int m = 0; m < 4; ++m)
#pragma unroll
            for (int n = 0; n < 4; ++n)
                acc[m][n] = __builtin_amdgcn_mfma_f32_16x16x32_bf16(af[m], bfr[n], acc[m][n], 0, 0, 0);
        __builtin_amdgcn_s_setprio(0);
    }
#undef WAITV

    __syncthreads();   // all waves done reading the ring before LDS reuse (WAR)

    // ---- epilogue: wave-private 8KB LDS stage, then 16B/lane stores.
    unsigned short* S = ((unsigned short*)LDSb) + wid * 4096;
    const bool relu_tile = (n0 < 1024);
#pragma unroll
    for (int m = 0; m < 4; ++m) {
        int rbase = m * 16 + ((lane >> 4) << 2);
#pragma unroll
        for (int n = 0; n < 4; ++n) {
            int col = n * 16 + lr;
#pragma unroll
            for (int r = 0; r < 4; ++r) {
                float v = acc[m][n][r];
                if (relu_tile && v < 0.0f) v = 0.0f;
                S[eoff(rbase + r, col)] = f2bf(v);
            }
        }
    }
    __syncthreads();   // order ds_writes before ds_reads
    {
        int rsub = lane >> 3, sub = lane & 7;
        size_t grow = (size_t)(m0 + wr * 64);
        int gcol = n0 + wc * 64 + sub * 8;
#pragma unroll
        for (int rd = 0; rd < 8; ++rd) {
            int row = rd * 8 + rsub;
            short8 vv = *(const short8*)&S[eoff(row, sub * 8)];
            *(short8*)(qkv + (grow + row) * TRIPLE + gcol) = vv;
        }
    }
}

// ---------------------------------------------------------------------------
// k_qkv_f: fallback (round-1 kernel) if ws too small for bf16 x copy.
__global__ __launch_bounds__(256) void k_qkv_f(const float* __restrict__ x,
        const unsigned short* __restrict__ wT,
        unsigned short* __restrict__ qkv)
{
    __shared__ unsigned short As[128][40];
    __shared__ unsigned short Bs[128][40];
    int t = threadIdx.x;
    int lane = t & 63, wave = t >> 6;
    int m0 = blockIdx.y * 128;
    int n0 = blockIdx.x * 128;
    int wm = (wave & 1) * 64, wn = (wave >> 1) * 64;
    int lr = lane & 15, kg = (lane >> 4) * 8;

    f32x4 acc[4][4] = {};
    for (int k0 = 0; k0 < DIM_; k0 += 32) {
#pragma unroll
        for (int i = 0; i < 4; ++i) {
            int c = t + 256 * i;
            int r = c >> 3, c4 = (c & 7) * 4;
            fl4 v = *(const fl4*)(x + (size_t)(m0 + r) * DIM_ + k0 + c4);
            unsigned short* dst = &As[r][c4];
            dst[0] = f2bf(v[0]); dst[1] = f2bf(v[1]); dst[2] = f2bf(v[2]); dst[3] = f2bf(v[3]);
        }
#pragma unroll
        for (int i = 0; i < 2; ++i) {
            int c = t + 256 * i;
            int r = c >> 2, c8 = (c & 3) * 8;
            *(int4*)&Bs[r][c8] = *(const int4*)(wT + (size_t)(n0 + r) * DIM_ + k0 + c8);
        }
        __syncthreads();
        short8 af[4], bfr[4];
#pragma unroll
        for (int i = 0; i < 4; ++i) af[i]  = *(short8*)&As[wm + i*16 + lr][kg];
#pragma unroll
        for (int j = 0; j < 4; ++j) bfr[j] = *(short8*)&Bs[wn + j*16 + lr][kg];
#pragma unroll
        for (int i = 0; i < 4; ++i)
#pragma unroll
            for (int j = 0; j < 4; ++j)
                acc[i][j] = __builtin_amdgcn_mfma_f32_16x16x32_bf16(af[i], bfr[j], acc[i][j], 0, 0, 0);
        __syncthreads();
    }
#pragma unroll
    for (int i = 0; i < 4; ++i) {
        int row = m0 + wm + i*16 + (lane >> 4) * 4;
#pragma unroll
        for (int j = 0; j < 4; ++j) {
            int col = n0 + wn + j*16 + (lane & 15);
            bool rl = (col < 1024);
#pragma unroll
            for (int r = 0; r < 4; ++r) {
                float v = acc[i][j][r];
                if (rl && v < 0.0f) v = 0.0f;
                qkv[(size_t)(row + r) * TRIPLE + col] = f2bf(v);
            }
        }
    }
}

// ---------------------------------------------------------------------------
// k_kv: kv[b,h] (64x64) = sum_n relu(k)[n][m] * v[n][d].  (round-8 proven)
__global__ __launch_bounds__(256) void k_kv(const unsigned short* __restrict__ qkv,
                                            float* __restrict__ kv) // [64][64][64] fp32
{
    __shared__ unsigned short KT[64][136];
    __shared__ unsigned short VT[64][136];
    __shared__ float red[64 * 64];
    int t = threadIdx.x, lane = t & 63, wave = t >> 6;
    int bh = blockIdx.x;
    int b = bh >> 3, h = bh & 7;
    int chunk = blockIdx.y;
    size_t rowbase = (size_t)b * N_ + (size_t)chunk * 1024;
    int kcol = DIM_ + h * 64;
    int vcol = 2 * DIM_ + h * 64;
    int lr = lane & 15;

    f32x4 acc[4][4] = {};
    for (int tile = 0; tile < 8; ++tile) {
        size_t r0 = rowbase + tile * 128;
#pragma unroll
        for (int i = 0; i < 2; ++i) {
            int u = t + 256 * i;            // 0..511
            int rp = u >> 3;                // row-pair 0..63
            int c8 = (u & 7) * 8;           // feature col 0..56
            size_t ra = r0 + 2 * rp, rb = ra + 1;
            us8 ka = *(const us8*)(qkv + ra * TRIPLE + kcol + c8);
            us8 kb = *(const us8*)(qkv + rb * TRIPLE + kcol + c8);
            us8 va = *(const us8*)(qkv + ra * TRIPLE + vcol + c8);
            us8 vb = *(const us8*)(qkv + rb * TRIPLE + vcol + c8);
#pragma unroll
            for (int j = 0; j < 8; ++j) {
                int d = c8 + j;
                *(unsigned int*)&KT[d][2 * rp] =
                    (unsigned int)ka[j] | ((unsigned int)kb[j] << 16);
                *(unsigned int*)&VT[d][2 * rp] =
                    (unsigned int)va[j] | ((unsigned int)vb[j] << 16);
            }
        }
        __syncthreads();
        int kg = wave * 32 + (lane >> 4) * 8;
        short8 af[4], bfr[4];
#pragma unroll
        for (int i = 0; i < 4; ++i) af[i]  = *(short8*)&KT[i*16 + lr][kg];
#pragma unroll
        for (int j = 0; j < 4; ++j) bfr[j] = *(short8*)&VT[j*16 + lr][kg];
#pragma unroll
        for (int i = 0; i < 4; ++i)
#pragma unroll
            for (int j = 0; j < 4; ++j)
                acc[i][j] = __builtin_amdgcn_mfma_f32_16x16x32_bf16(af[i], bfr[j], acc[i][j], 0, 0, 0);
        __syncthreads();
    }
    for (int w = 0; w < 4; ++w) {
        if (wave == w) {
#pragma unroll
            for (int i = 0; i < 4; ++i)
#pragma unroll
                for (int j = 0; j < 4; ++j)
#pragma unroll
                    for (int r = 0; r < 4; ++r) {
                        int m = i*16 + (lane >> 4) * 4 + r;
                        int d = j*16 + (lane & 15);
                        if (w == 0) red[m * 64 + d] = acc[i][j][r];
                        else        red[m * 64 + d] += acc[i][j][r];
                    }
        }
        __syncthreads();
    }
    float* kvout = kv + (size_t)bh * 4096;
#pragma unroll
    for (int i = 0; i < 16; ++i) {
        int idx = t + 256 * i;
        atomicAdd(&kvout[idx], red[idx]);
    }
}

// ---------------------------------------------------------------------------
// k_kvt: kvbuf fp32 [bh][m][d] -> kvtb bf16 [bh][d][m] (transpose+convert).
__global__ __launch_bounds__(256) void k_kvt(const float* __restrict__ kv,
                                             unsigned short* __restrict__ kvtb) {
    __shared__ float T[64][65];
    int bh = blockIdx.x, t = threadIdx.x;
    const float* src = kv + (size_t)bh * 4096;
    unsigned short* dst = kvtb + (size_t)bh * 4096;
#pragma unroll
    for (int i = 0; i < 16; ++i) {
        int idx = t + 256 * i;                 // m*64 + d
        T[idx & 63][idx >> 6] = src[idx];      // T[d][m]
    }
    __syncthreads();
#pragma unroll
    for (int i = 0; i < 16; ++i) {
        int idx = t + 256 * i;                 // d*64 + m
        dst[idx] = f2bf(T[idx >> 6][idx & 63]);
    }
}

// ---------------------------------------------------------------------------
// k_ao: FUSED attn + LayerNorm + out-GEMM, 512 threads (8 waves).
//   ROUND-12 FIX: __launch_bounds__(512, 2) -> 256-VGPR cap.  Round 11's
//   bare (512) let the compiler cap at 128 VGPR; phase 3 needs ~200 live
//   (acc[8][4]=128 + af[8]+bfr[4]) -> scratch spill (WRITE_SIZE +24MB,
//   MfmaUtil 0.9%).  With 136KB LDS -> 1 block/CU, 2 waves/SIMD: 256 cap
//   is exactly the budget.  Structure otherwise identical to round 11.
__global__ __launch_bounds__(512, 2) void k_ao(
        const unsigned short* __restrict__ qkv,
        const unsigned short* __restrict__ kvtb,
        const float* __restrict__ lnw, const float* __restrict__ lnb,
        const unsigned short* __restrict__ woutT,
        const float* __restrict__ bout, float* __restrict__ out)
{
    __shared__ unsigned short attnS[128 * 512];          // 128 KB, swizzled
    __shared__ float lwS[512], lbS[512], muS[128], rsS[128];
    int t = threadIdx.x, lane = t & 63, wave = t >> 6;   // wave 0..7
    int lr = lane & 15;
    size_t r0 = (size_t)blockIdx.x * 128;
    int b = (int)(r0 / N_);

    for (int i = t; i < 512; i += 512) { lwS[i] = lnw[i]; lbS[i] = lnb[i]; }

    float s4[4] = {}, ss4[4] = {};   // per-row LN partials (4 rows/thread)

#pragma unroll
    for (int h = 0; h < H_; ++h) {
        const unsigned short* kvh = kvtb + (size_t)(b * 8 + h) * 4096;
        f32x4 acc[4] = {};
#pragma unroll
        for (int ks = 0; ks < 2; ++ks) {
            int kg = ks * 32 + (lane >> 4) * 8;
            short8 af, bfr[4];
            af = *(const short8*)(qkv + (r0 + wave * 16 + lr) * TRIPLE + h * 64 + kg);
#pragma unroll
            for (int j = 0; j < 4; ++j)
                bfr[j] = *(const short8*)(kvh + (j * 16 + lr) * 64 + kg);
#pragma unroll
            for (int j = 0; j < 4; ++j)
                acc[j] = __builtin_amdgcn_mfma_f32_16x16x32_bf16(af, bfr[j], acc[j], 0, 0, 0);
        }
        // stats from f32 accs + write attn tile into swizzled LDS
        int rbase = wave * 16 + (lane >> 4) * 4;
#pragma unroll
        for (int j = 0; j < 4; ++j) {
            int col = h * 64 + j * 16 + lr;
#pragma unroll
            for (int r = 0; r < 4; ++r) {
                float v = acc[j][r];
                s4[r] += v;
                ss4[r] += v * v;
                attnS[aoff(rbase + r, col)] = f2bf(v);
            }
        }
    }

    // reduce stats across the 16 col-lanes (lane bits 0..3)
#pragma unroll
    for (int q = 0; q < 4; ++q) {
        float s = s4[q], ss = ss4[q];
        s += __shfl_xor(s, 1);  ss += __shfl_xor(ss, 1);
        s += __shfl_xor(s, 2);  ss += __shfl_xor(ss, 2);
        s += __shfl_xor(s, 4);  ss += __shfl_xor(ss, 4);
        s += __shfl_xor(s, 8);  ss += __shfl_xor(ss, 8);
        s4[q] = s; ss4[q] = ss;
    }
    if (lr == 0) {
#pragma unroll
        for (int q = 0; q < 4; ++q) {
            int row = wave * 16 + (lane >> 4) * 4 + q;
            float m = s4[q] * (1.0f / 512.0f);
            muS[row] = m;
            rsS[row] = rsqrtf(ss4[q] * (1.0f / 512.0f) - m * m + EPS_);
        }
    }
    __syncthreads();   // attnS complete + stats visible

    // LN in place: thread -> row t>>2, quarter (t&3)*16 granules of 8 ushort
    {
        int row = t >> 2, ch = (t & 3) * 16;
        float mm = muS[row], rr = rsS[row];
        unsigned short* base = attnS + row * 512;
#pragma unroll
        for (int g = 0; g < 16; ++g) {
            int colg = ch + g;
            us8* p = (us8*)(base + ((colg ^ (row & 7)) << 3));
            us8 v = *p, o;
#pragma unroll
            for (int j = 0; j < 8; ++j)
                o[j] = f2bf((bf2f(v[j]) - mm) * rr * lwS[colg * 8 + j] + lbS[colg * 8 + j]);
            *p = o;
        }
    }
    __syncthreads();   // LN'd attnS stable; read-only below (no more barriers)

    // out-GEMM: wave owns cols wave*64..+63
    {
        int ncol = wave * 64;
        f32x4 acc[8][4] = {};
        for (int k0 = 0; k0 < 512; k0 += 32) {
            int gk = (k0 >> 3) + (lane >> 4);
            short8 af[8], bfr[4];
#pragma unroll
            for (int m = 0; m < 8; ++m) {
                int row = m * 16 + lr;
                af[m] = *(const short8*)&attnS[row * 512 + ((gk ^ (row & 7)) << 3)];
            }
#pragma unroll
            for (int j = 0; j < 4; ++j)
                bfr[j] = *(const short8*)(woutT + (size_t)(ncol + j * 16 + lr) * 512 + k0 + (lane >> 4) * 8);
#pragma unroll
            for (int m = 0; m < 8; ++m)
#pragma unroll
                for (int j = 0; j < 4; ++j)
                    acc[m][j] = __builtin_amdgcn_mfma_f32_16x16x32_bf16(af[m], bfr[j], acc[m][j], 0, 0, 0);
        }
#pragma unroll
        for (int m = 0; m < 8; ++m) {
            size_t row = r0 + m * 16 + ((lane >> 4) << 2);
#pragma unroll
            for (int j = 0; j < 4; ++j) {
                int col = ncol + j * 16 + (lane & 15);
                float bo = bout[col];
#pragma unroll
                for (int r = 0; r < 4; ++r)
                    out[(row + r) * DIM_ + col] = acc[m][j][r] + bo;
            }
        }
    }
}

// ---------------------------------------------------------------------------
extern "C" void kernel_launch(void* const* d_in, const int* in_sizes, int n_in,
                              void* d_out, int out_size, void* d_ws, size_t ws_size,
                              hipStream_t stream) {
    (void)in_sizes; (void)n_in; (void)out_size;
    const float* x     = (const float*)d_in[0];
    const float* w_qkv = (const float*)d_in[1];
    const float* ln_w  = (const float*)d_in[2];
    const float* ln_b  = (const float*)d_in[3];
    const float* w_out = (const float*)d_in[4];
    const float* b_out = (const float*)d_in[5];
    float* out = (float*)d_out;

    char* ws = (char*)d_ws;
    const size_t QKV_BYTES = (size_t)ROWS * TRIPLE * sizeof(unsigned short); // 201326592
    const size_t KV_BYTES  = (size_t)64 * 64 * 64 * sizeof(float);           // 1048576
    const size_t WQT_BYTES = (size_t)TRIPLE * DIM_ * sizeof(unsigned short); // 1572864
    const size_t WOT_BYTES = (size_t)DIM_ * DIM_ * sizeof(unsigned short);   // 524288
    const size_t KVT_BYTES = (size_t)64 * 64 * 64 * sizeof(unsigned short);  // 524288
    const size_t XB_BYTES  = (size_t)ROWS * DIM_ * sizeof(unsigned short);   // 67108864
    unsigned short* qkv   = (unsigned short*)ws;
    float*          kvbuf = (float*)(ws + QKV_BYTES);
    unsigned short* wqkvT = (unsigned short*)(ws + QKV_BYTES + KV_BYTES);
    unsigned short* woutT = (unsigned short*)(ws + QKV_BYTES + KV_BYTES + WQT_BYTES);
    unsigned short* kvtb  = (unsigned short*)(ws + QKV_BYTES + KV_BYTES + WQT_BYTES + WOT_BYTES);
    unsigned short* xb    = (unsigned short*)(ws + QKV_BYTES + KV_BYTES + WQT_BYTES + WOT_BYTES + KVT_BYTES);
    const size_t NEED = QKV_BYTES + KV_BYTES + WQT_BYTES + WOT_BYTES + KVT_BYTES + XB_BYTES;

    hipMemsetAsync(kvbuf, 0, KV_BYTES, stream);
    k_prep<<<1024, 256, 0, stream>>>(w_qkv, w_out, wqkvT, woutT);
    if (ws_size >= NEED) {
        k_cvt<<<16384, 256, 0, stream>>>(x, xb);
        k_qkv8<<<dim3(3072), 512, 0, stream>>>(xb, wqkvT, qkv);
    } else {
        k_qkv_f<<<dim3(12, 512), 256, 0, stream>>>(x, wqkvT, qkv);
    }
    k_kv<<<dim3(64, 8), 256, 0, stream>>>(qkv, kvbuf);
    k_kvt<<<64, 256, 0, stream>>>(kvbuf, kvtb);
    k_ao<<<512, 512, 0, stream>>>(qkv, kvtb, ln_w, ln_b, woutT, b_out, out);
}

// Round 13
// 491.702 us; speedup vs baseline: 1.0169x; 1.0169x over previous
//
#include <hip/hip_runtime.h>
#include <stdint.h>

#define B_ 8
#define N_ 8192
#define DIM_ 512
#define H_ 8
#define DH_ 64
#define ROWS (B_*N_)        // 65536
#define TRIPLE (3*DIM_)     // 1536
#define EPS_ 1e-5f
#define PLANE ((size_t)ROWS * 64)   // one head-plane: [65536][64] ushort

typedef __attribute__((ext_vector_type(8))) short short8;
typedef __attribute__((ext_vector_type(4))) float f32x4;
typedef __attribute__((ext_vector_type(4))) float fl4;
typedef __attribute__((ext_vector_type(4))) unsigned short us4;
typedef __attribute__((ext_vector_type(8))) unsigned short us8;

#define AS1 __attribute__((address_space(1)))
#define AS3 __attribute__((address_space(3)))

__device__ __forceinline__ void gld16(const void* g, void* l) {
    // async global->LDS, 16B/lane; LDS dest = wave-uniform base + lane*16
    __builtin_amdgcn_global_load_lds((const AS1 void*)(uintptr_t)g,
                                     (AS3 void*)(unsigned)(uintptr_t)l, 16, 0, 0);
}

__device__ inline unsigned short f2bf(float f) {
    union { float f; unsigned int u; } x; x.f = f;
    unsigned int r = x.u + 0x7fffu + ((x.u >> 16) & 1u);
    return (unsigned short)(r >> 16);
}
__device__ inline float bf2f(unsigned short b) {
    union { unsigned int u; float f; } x; x.u = ((unsigned int)b) << 16;
    return x.f;
}

// epilogue LDS swizzle (k_qkv8): XOR the 32B-block index by the fragment
// row-group so the 4 row-groups of one fragment-store hit disjoint octets.
__device__ __forceinline__ int eoff(int row, int col) {
    return row * 64 + (col ^ ((((unsigned)row >> 2) & 3) << 4));
}

// attnS swizzle (k_ao): XOR the 8-ushort granule index by row&7 so the
// 16-row fragment reads (stride 1024B) spread across 8 bank-quads (2-way).
__device__ __forceinline__ int aoff(int row, int col) {
    return row * 512 + ((((col >> 3) ^ (row & 7)) << 3) | (col & 7));
}

// ---------------------------------------------------------------------------
// k_cvt: x fp32 -> bf16 (row-major unchanged), enables async A-staging in k_qkv
__global__ __launch_bounds__(256) void k_cvt(const float* __restrict__ x,
                                             unsigned short* __restrict__ xb) {
    size_t i = ((size_t)blockIdx.x * 256 + threadIdx.x) * 8;
    fl4 a = *(const fl4*)(x + i);
    fl4 b = *(const fl4*)(x + i + 4);
    us8 r;
    r[0] = f2bf(a[0]); r[1] = f2bf(a[1]); r[2] = f2bf(a[2]); r[3] = f2bf(a[3]);
    r[4] = f2bf(b[0]); r[5] = f2bf(b[1]); r[6] = f2bf(b[2]); r[7] = f2bf(b[3]);
    *(us8*)(xb + i) = r;
}

// ---------------------------------------------------------------------------
// k_prep: coalesced LDS-tiled transpose+convert of both weights to bf16 [n][k].
__global__ __launch_bounds__(256) void k_prep(const float* __restrict__ wq,
        const float* __restrict__ wo,
        unsigned short* __restrict__ wqT, unsigned short* __restrict__ woT) {
    __shared__ float T[32][33];
    int bid = blockIdx.x;
    const float* src; unsigned short* dst; int srcCols, dstCols, k0, n0;
    if (bid < 768) {                  // w_qkv: [512][1536] -> [1536][512]
        int tn = bid % 48, tk = bid / 48;
        src = wq; dst = wqT; srcCols = 1536; dstCols = 512;
        k0 = tk * 32; n0 = tn * 32;
    } else {                          // w_out: [512][512] -> [512][512]
        int b = bid - 768;
        int tn = b % 16, tk = b / 16;
        src = wo; dst = woT; srcCols = 512; dstCols = 512;
        k0 = tk * 32; n0 = tn * 32;
    }
    int t = threadIdx.x, r = t >> 3, c4 = (t & 7) * 4;
    fl4 v = *(const fl4*)(src + (size_t)(k0 + r) * srcCols + n0 + c4);
    T[c4 + 0][r] = v[0]; T[c4 + 1][r] = v[1];
    T[c4 + 2][r] = v[2]; T[c4 + 3][r] = v[3];
    __syncthreads();
    us4 o;
    o[0] = f2bf(T[r][c4 + 0]); o[1] = f2bf(T[r][c4 + 1]);
    o[2] = f2bf(T[r][c4 + 2]); o[3] = f2bf(T[r][c4 + 3]);
    *(us4*)(dst + (size_t)(n0 + r) * dstCols + k0 + c4) = o;
}

// ---------------------------------------------------------------------------
// k_qkv8: round-7..12 proven K-loop, VERBATIM (256x128 tile, BK=32, ring-3,
//   depth-2, counted vmcnt(3), 2 blocks/CU).  ROUND-13: output is now
//   HEAD-PLANAR qkv [24][65536][64] — each wave's 64-col chunk = one plane,
//   so the epilogue stores are contiguous 1KB streams (DRAM-locality fix).
__global__ __launch_bounds__(512, 4) void k_qkv8(const unsigned short* __restrict__ xb,
        const unsigned short* __restrict__ wT,      // [1536][512] bf16
        unsigned short* __restrict__ qkv)           // [24][65536][64] bf16
{
    // slot layout: A = ushort [0, 8192) (256x32), B = [8192, 12288) (128x32)
    __shared__ __align__(1024) unsigned short LDSb[3][12288];   // 72 KB

    const int tid  = threadIdx.x;
    const int lane = tid & 63;
    const int wid  = tid >> 6;     // 0..7
    const int wr   = wid >> 1;     // 0..3  (M quarter, 64 rows)
    const int wc   = wid & 1;      // 0..1  (N half, 64 cols)
    const int lr   = lane & 15;

    // bijective XCD swizzle (3072 % 8 == 0): 12 N-blocks share an A-panel
    // within one XCD's 384-block chunk.
    int id  = blockIdx.x;
    int nid = (id & 7) * 384 + (id >> 3);
    int n0  = (nid % 12) * 128;
    int m0  = (nid / 12) * 256;

    // ---- staging source coords (inverse of st_16x32 swizzle; LDS dest linear)
    const unsigned short* pA[2];
    const unsigned short* pB1;
    unsigned ldstA[2], ldstB;
#pragma unroll
    for (int j = 0; j < 2; ++j) {
        int s    = tid + j * 512;
        int row  = ((s >> 6) << 4) + ((s >> 2) & 15);
        int colb = ((s & 3) << 4) ^ (((s >> 5) & 1) << 5);
        pA[j] = xb + (size_t)(m0 + row) * 512 + (colb >> 1);
        ldstA[j] = (unsigned)((j * 512 + wid * 64) * 8);   // ushort idx
    }
    {
        int s    = tid;
        int row  = ((s >> 6) << 4) + ((s >> 2) & 15);
        int colb = ((s & 3) << 4) ^ (((s >> 5) & 1) << 5);
        pB1 = wT + (size_t)(n0 + row) * 512 + (colb >> 1);
        ldstB = (unsigned)(8192 + wid * 64 * 8);
    }
    // swizzled ds_read lane offset (ushort idx within a subtile)
    const int kg = (lane >> 4) * 8;
    const int lo = lr * 32 + (kg ^ ((lr >> 3) << 4));

    auto STAGE = [&](int t, int slot) {
        gld16(pA[0] + t * 32, (void*)&LDSb[slot][ldstA[0]]);
        gld16(pA[1] + t * 32, (void*)&LDSb[slot][ldstA[1]]);
        gld16(pB1   + t * 32, (void*)&LDSb[slot][ldstB]);
    };

    f32x4 acc[4][4] = {};
    short8 af[4], bfr[4];

    STAGE(0, 0);
    STAGE(1, 1);

#define WAITV(n) asm volatile("s_waitcnt vmcnt(" #n ")" ::: "memory")
#pragma unroll
    for (int t = 0; t < 16; ++t) {
        // outstanding at top: tiles t (3) + t+1 (3); leave t+1's in flight.
        if (t <= 14) WAITV(3);
        else         WAITV(0);
        __builtin_amdgcn_s_barrier();          // all waves' tile-t loads landed
        __builtin_amdgcn_sched_barrier(0);     // pin: nothing hoists above

        if (t + 2 < 16) STAGE(t + 2, (t + 2) % 3);  // slot (t-1)%3: readers done

        const unsigned short* L = LDSb[t % 3];
#pragma unroll
        for (int m = 0; m < 4; ++m)
            af[m] = *(const short8*)&L[(wr * 4 + m) * 512 + lo];
#pragma unroll
        for (int n = 0; n < 4; ++n)
            bfr[n] = *(const short8*)&L[8192 + (wc * 4 + n) * 512 + lo];

        __builtin_amdgcn_s_setprio(1);
#pragma unroll
        for (int m = 0; m < 4; ++m)
#pragma unroll
            for (int n = 0; n < 4; ++n)
                acc[m][n] = __builtin_amdgcn_mfma_f32_16x16x32_bf16(af[m], bfr[n], acc[m][n], 0, 0, 0);
        __builtin_amdgcn_s_setprio(0);
    }
#undef WAITV

    __syncthreads();   // all waves done reading the ring before LDS reuse (WAR)

    // ---- epilogue: wave-private 8KB LDS stage, then contiguous plane stores.
    unsigned short* S = ((unsigned short*)LDSb) + wid * 4096;
    const bool relu_tile = (n0 < 1024);
#pragma unroll
    for (int m = 0; m < 4; ++m) {
        int rbase = m * 16 + ((lane >> 4) << 2);
#pragma unroll
        for (int n = 0; n < 4; ++n) {
            int col = n * 16 + lr;
#pragma unroll
            for (int r = 0; r < 4; ++r) {
                float v = acc[m][n][r];
                if (relu_tile && v < 0.0f) v = 0.0f;
                S[eoff(rbase + r, col)] = f2bf(v);
            }
        }
    }
    __syncthreads();   // order ds_writes before ds_reads
    {
        int rsub = lane >> 3, sub = lane & 7;
        size_t grow = (size_t)(m0 + wr * 64);
        unsigned short* pb = qkv + (size_t)((n0 >> 6) + wc) * PLANE;
#pragma unroll
        for (int rd = 0; rd < 8; ++rd) {
            int row = rd * 8 + rsub;
            short8 vv = *(const short8*)&S[eoff(row, sub * 8)];
            *(short8*)(pb + (grow + row) * 64 + sub * 8) = vv;
        }
    }
}

// ---------------------------------------------------------------------------
// k_qkv_f: fallback (round-1 kernel) if ws too small for bf16 x copy.
//   Updated for head-planar qkv output.
__global__ __launch_bounds__(256) void k_qkv_f(const float* __restrict__ x,
        const unsigned short* __restrict__ wT,
        unsigned short* __restrict__ qkv)
{
    __shared__ unsigned short As[128][40];
    __shared__ unsigned short Bs[128][40];
    int t = threadIdx.x;
    int lane = t & 63, wave = t >> 6;
    int m0 = blockIdx.y * 128;
    int n0 = blockIdx.x * 128;
    int wm = (wave & 1) * 64, wn = (wave >> 1) * 64;
    int lr = lane & 15, kg = (lane >> 4) * 8;

    f32x4 acc[4][4] = {};
    for (int k0 = 0; k0 < DIM_; k0 += 32) {
#pragma unroll
        for (int i = 0; i < 4; ++i) {
            int c = t + 256 * i;
            int r = c >> 3, c4 = (c & 7) * 4;
            fl4 v = *(const fl4*)(x + (size_t)(m0 + r) * DIM_ + k0 + c4);
            unsigned short* dst = &As[r][c4];
            dst[0] = f2bf(v[0]); dst[1] = f2bf(v[1]); dst[2] = f2bf(v[2]); dst[3] = f2bf(v[3]);
        }
#pragma unroll
        for (int i = 0; i < 2; ++i) {
            int c = t + 256 * i;
            int r = c >> 2, c8 = (c & 3) * 8;
            *(int4*)&Bs[r][c8] = *(const int4*)(wT + (size_t)(n0 + r) * DIM_ + k0 + c8);
        }
        __syncthreads();
        short8 af[4], bfr[4];
#pragma unroll
        for (int i = 0; i < 4; ++i) af[i]  = *(short8*)&As[wm + i*16 + lr][kg];
#pragma unroll
        for (int j = 0; j < 4; ++j) bfr[j] = *(short8*)&Bs[wn + j*16 + lr][kg];
#pragma unroll
        for (int i = 0; i < 4; ++i)
#pragma unroll
            for (int j = 0; j < 4; ++j)
                acc[i][j] = __builtin_amdgcn_mfma_f32_16x16x32_bf16(af[i], bfr[j], acc[i][j], 0, 0, 0);
        __syncthreads();
    }
#pragma unroll
    for (int i = 0; i < 4; ++i) {
        int row = m0 + wm + i*16 + (lane >> 4) * 4;
#pragma unroll
        for (int j = 0; j < 4; ++j) {
            int col = n0 + wn + j*16 + (lane & 15);
            bool rl = (col < 1024);
            size_t pbase = (size_t)(col >> 6) * PLANE + (col & 63);
#pragma unroll
            for (int r = 0; r < 4; ++r) {
                float v = acc[i][j][r];
                if (rl && v < 0.0f) v = 0.0f;
                qkv[pbase + (size_t)(row + r) * 64] = f2bf(v);
            }
        }
    }
}

// ---------------------------------------------------------------------------
// k_kv: kv[b,h] (64x64) = sum_n relu(k)[n][m] * v[n][d].
//   ROUND-13: reads head-planar K/V planes — fully contiguous 128KB slabs
//   per block instead of 128B-in-3072B strides.
__global__ __launch_bounds__(256) void k_kv(const unsigned short* __restrict__ qkv,
                                            float* __restrict__ kv) // [64][64][64] fp32
{
    __shared__ unsigned short KT[64][136];
    __shared__ unsigned short VT[64][136];
    __shared__ float red[64 * 64];
    int t = threadIdx.x, lane = t & 63, wave = t >> 6;
    int bh = blockIdx.x;
    int b = bh >> 3, h = bh & 7;
    int chunk = blockIdx.y;
    size_t rowbase = (size_t)b * N_ + (size_t)chunk * 1024;
    const unsigned short* kp = qkv + (size_t)(8 + h) * PLANE;    // K plane
    const unsigned short* vp = qkv + (size_t)(16 + h) * PLANE;   // V plane
    int lr = lane & 15;

    f32x4 acc[4][4] = {};
    for (int tile = 0; tile < 8; ++tile) {
        size_t r0 = rowbase + tile * 128;
#pragma unroll
        for (int i = 0; i < 2; ++i) {
            int u = t + 256 * i;            // 0..511
            int rp = u >> 3;                // row-pair 0..63
            int c8 = (u & 7) * 8;           // feature col 0..56
            size_t ra = r0 + 2 * rp, rb = ra + 1;
            us8 ka = *(const us8*)(kp + ra * 64 + c8);
            us8 kb = *(const us8*)(kp + rb * 64 + c8);
            us8 va = *(const us8*)(vp + ra * 64 + c8);
            us8 vb = *(const us8*)(vp + rb * 64 + c8);
#pragma unroll
            for (int j = 0; j < 8; ++j) {
                int d = c8 + j;
                *(unsigned int*)&KT[d][2 * rp] =
                    (unsigned int)ka[j] | ((unsigned int)kb[j] << 16);
                *(unsigned int*)&VT[d][2 * rp] =
                    (unsigned int)va[j] | ((unsigned int)vb[j] << 16);
            }
        }
        __syncthreads();
        int kg = wave * 32 + (lane >> 4) * 8;
        short8 af[4], bfr[4];
#pragma unroll
        for (int i = 0; i < 4; ++i) af[i]  = *(short8*)&KT[i*16 + lr][kg];
#pragma unroll
        for (int j = 0; j < 4; ++j) bfr[j] = *(short8*)&VT[j*16 + lr][kg];
#pragma unroll
        for (int i = 0; i < 4; ++i)
#pragma unroll
            for (int j = 0; j < 4; ++j)
                acc[i][j] = __builtin_amdgcn_mfma_f32_16x16x32_bf16(af[i], bfr[j], acc[i][j], 0, 0, 0);
        __syncthreads();
    }
    for (int w = 0; w < 4; ++w) {
        if (wave == w) {
#pragma unroll
            for (int i = 0; i < 4; ++i)
#pragma unroll
                for (int j = 0; j < 4; ++j)
#pragma unroll
                    for (int r = 0; r < 4; ++r) {
                        int m = i*16 + (lane >> 4) * 4 + r;
                        int d = j*16 + (lane & 15);
                        if (w == 0) red[m * 64 + d] = acc[i][j][r];
                        else        red[m * 64 + d] += acc[i][j][r];
                    }
        }
        __syncthreads();
    }
    float* kvout = kv + (size_t)bh * 4096;
#pragma unroll
    for (int i = 0; i < 16; ++i) {
        int idx = t + 256 * i;
        atomicAdd(&kvout[idx], red[idx]);
    }
}

// ---------------------------------------------------------------------------
// k_kvt: kvbuf fp32 [bh][m][d] -> kvtb bf16 [bh][d][m] (transpose+convert).
__global__ __launch_bounds__(256) void k_kvt(const float* __restrict__ kv,
                                             unsigned short* __restrict__ kvtb) {
    __shared__ float T[64][65];
    int bh = blockIdx.x, t = threadIdx.x;
    const float* src = kv + (size_t)bh * 4096;
    unsigned short* dst = kvtb + (size_t)bh * 4096;
#pragma unroll
    for (int i = 0; i < 16; ++i) {
        int idx = t + 256 * i;                 // m*64 + d
        T[idx & 63][idx >> 6] = src[idx];      // T[d][m]
    }
    __syncthreads();
#pragma unroll
    for (int i = 0; i < 16; ++i) {
        int idx = t + 256 * i;                 // d*64 + m
        dst[idx] = f2bf(T[idx >> 6][idx & 63]);
    }
}

// ---------------------------------------------------------------------------
// k_ao: FUSED attn + LayerNorm + out-GEMM, 512 threads (8 waves), (512,2).
//   ROUND-13: Q read from head-planar qkv — contiguous 16KB slab per head
//   per block instead of 128B-in-3072B strides.
__global__ __launch_bounds__(512, 2) void k_ao(
        const unsigned short* __restrict__ qkv,
        const unsigned short* __restrict__ kvtb,
        const float* __restrict__ lnw, const float* __restrict__ lnb,
        const unsigned short* __restrict__ woutT,
        const float* __restrict__ bout, float* __restrict__ out)
{
    __shared__ unsigned short attnS[128 * 512];          // 128 KB, swizzled
    __shared__ float lwS[512], lbS[512], muS[128], rsS[128];
    int t = threadIdx.x, lane = t & 63, wave = t >> 6;   // wave 0..7
    int lr = lane & 15;
    size_t r0 = (size_t)blockIdx.x * 128;
    int b = (int)(r0 / N_);

    for (int i = t; i < 512; i += 512) { lwS[i] = lnw[i]; lbS[i] = lnb[i]; }

    float s4[4] = {}, ss4[4] = {};   // per-row LN partials (4 rows/thread)

#pragma unroll
    for (int h = 0; h < H_; ++h) {
        const unsigned short* qp  = qkv + (size_t)h * PLANE;       // Q plane
        const unsigned short* kvh = kvtb + (size_t)(b * 8 + h) * 4096;
        f32x4 acc[4] = {};
#pragma unroll
        for (int ks = 0; ks < 2; ++ks) {
            int kg = ks * 32 + (lane >> 4) * 8;
            short8 af, bfr[4];
            af = *(const short8*)(qp + (r0 + wave * 16 + lr) * 64 + kg);
#pragma unroll
            for (int j = 0; j < 4; ++j)
                bfr[j] = *(const short8*)(kvh + (j * 16 + lr) * 64 + kg);
#pragma unroll
            for (int j = 0; j < 4; ++j)
                acc[j] = __builtin_amdgcn_mfma_f32_16x16x32_bf16(af, bfr[j], acc[j], 0, 0, 0);
        }
        // stats from f32 accs + write attn tile into swizzled LDS
        int rbase = wave * 16 + (lane >> 4) * 4;
#pragma unroll
        for (int j = 0; j < 4; ++j) {
            int col = h * 64 + j * 16 + lr;
#pragma unroll
            for (int r = 0; r < 4; ++r) {
                float v = acc[j][r];
                s4[r] += v;
                ss4[r] += v * v;
                attnS[aoff(rbase + r, col)] = f2bf(v);
            }
        }
    }

    // reduce stats across the 16 col-lanes (lane bits 0..3)
#pragma unroll
    for (int q = 0; q < 4; ++q) {
        float s = s4[q], ss = ss4[q];
        s += __shfl_xor(s, 1);  ss += __shfl_xor(ss, 1);
        s += __shfl_xor(s, 2);  ss += __shfl_xor(ss, 2);
        s += __shfl_xor(s, 4);  ss += __shfl_xor(ss, 4);
        s += __shfl_xor(s, 8);  ss += __shfl_xor(ss, 8);
        s4[q] = s; ss4[q] = ss;
    }
    if (lr == 0) {
#pragma unroll
        for (int q = 0; q < 4; ++q) {
            int row = wave * 16 + (lane >> 4) * 4 + q;
            float m = s4[q] * (1.0f / 512.0f);
            muS[row] = m;
            rsS[row] = rsqrtf(ss4[q] * (1.0f / 512.0f) - m * m + EPS_);
        }
    }
    __syncthreads();   // attnS complete + stats visible

    // LN in place: thread -> row t>>2, quarter (t&3)*16 granules of 8 ushort
    {
        int row = t >> 2, ch = (t & 3) * 16;
        float mm = muS[row], rr = rsS[row];
        unsigned short* base = attnS + row * 512;
#pragma unroll
        for (int g = 0; g < 16; ++g) {
            int colg = ch + g;
            us8* p = (us8*)(base + ((colg ^ (row & 7)) << 3));
            us8 v = *p, o;
#pragma unroll
            for (int j = 0; j < 8; ++j)
                o[j] = f2bf((bf2f(v[j]) - mm) * rr * lwS[colg * 8 + j] + lbS[colg * 8 + j]);
            *p = o;
        }
    }
    __syncthreads();   // LN'd attnS stable; read-only below (no more barriers)

    // out-GEMM: wave owns cols wave*64..+63
    {
        int ncol = wave * 64;
        f32x4 acc[8][4] = {};
        for (int k0 = 0; k0 < 512; k0 += 32) {
            int gk = (k0 >> 3) + (lane >> 4);
            short8 af[8], bfr[4];
#pragma unroll
            for (int m = 0; m < 8; ++m) {
                int row = m * 16 + lr;
                af[m] = *(const short8*)&attnS[row * 512 + ((gk ^ (row & 7)) << 3)];
            }
#pragma unroll
            for (int j = 0; j < 4; ++j)
                bfr[j] = *(const short8*)(woutT + (size_t)(ncol + j * 16 + lr) * 512 + k0 + (lane >> 4) * 8);
#pragma unroll
            for (int m = 0; m < 8; ++m)
#pragma unroll
                for (int j = 0; j < 4; ++j)
                    acc[m][j] = __builtin_amdgcn_mfma_f32_16x16x32_bf16(af[m], bfr[j], acc[m][j], 0, 0, 0);
        }
#pragma unroll
        for (int m = 0; m < 8; ++m) {
            size_t row = r0 + m * 16 + ((lane >> 4) << 2);
#pragma unroll
            for (int j = 0; j < 4; ++j) {
                int col = ncol + j * 16 + (lane & 15);
                float bo = bout[col];
#pragma unroll
                for (int r = 0; r < 4; ++r)
                    out[(row + r) * DIM_ + col] = acc[m][j][r] + bo;
            }
        }
    }
}

// ---------------------------------------------------------------------------
extern "C" void kernel_launch(void* const* d_in, const int* in_sizes, int n_in,
                              void* d_out, int out_size, void* d_ws, size_t ws_size,
                              hipStream_t stream) {
    (void)in_sizes; (void)n_in; (void)out_size;
    const float* x     = (const float*)d_in[0];
    const float* w_qkv = (const float*)d_in[1];
    const float* ln_w  = (const float*)d_in[2];
    const float* ln_b  = (const float*)d_in[3];
    const float* w_out = (const float*)d_in[4];
    const float* b_out = (const float*)d_in[5];
    float* out = (float*)d_out;

    char* ws = (char*)d_ws;
    const size_t QKV_BYTES = (size_t)ROWS * TRIPLE * sizeof(unsigned short); // 201326592
    const size_t KV_BYTES  = (size_t)64 * 64 * 64 * sizeof(float);           // 1048576
    const size_t WQT_BYTES = (size_t)TRIPLE * DIM_ * sizeof(unsigned short); // 1572864
    const size_t WOT_BYTES = (size_t)DIM_ * DIM_ * sizeof(unsigned short);   // 524288
    const size_t KVT_BYTES = (size_t)64 * 64 * 64 * sizeof(unsigned short);  // 524288
    const size_t XB_BYTES  = (size_t)ROWS * DIM_ * sizeof(unsigned short);   // 67108864
    unsigned short* qkv   = (unsigned short*)ws;
    float*          kvbuf = (float*)(ws + QKV_BYTES);
    unsigned short* wqkvT = (unsigned short*)(ws + QKV_BYTES + KV_BYTES);
    unsigned short* woutT = (unsigned short*)(ws + QKV_BYTES + KV_BYTES + WQT_BYTES);
    unsigned short* kvtb  = (unsigned short*)(ws + QKV_BYTES + KV_BYTES + WQT_BYTES + WOT_BYTES);
    unsigned short* xb    = (unsigned short*)(ws + QKV_BYTES + KV_BYTES + WQT_BYTES + WOT_BYTES + KVT_BYTES);
    const size_t NEED = QKV_BYTES + KV_BYTES + WQT_BYTES + WOT_BYTES + KVT_BYTES + XB_BYTES;

    hipMemsetAsync(kvbuf, 0, KV_BYTES, stream);
    k_prep<<<1024, 256, 0, stream>>>(w_qkv, w_out, wqkvT, woutT);
    if (ws_size >= NEED) {
        k_cvt<<<16384, 256, 0, stream>>>(x, xb);
        k_qkv8<<<dim3(3072), 512, 0, stream>>>(xb, wqkvT, qkv);
    } else {
        k_qkv_f<<<dim3(12, 512), 256, 0, stream>>>(x, wqkvT, qkv);
    }
    k_kv<<<dim3(64, 8), 256, 0, stream>>>(qkv, kvbuf);
    k_kvt<<<64, 256, 0, stream>>>(kvbuf, kvtb);
    k_ao<<<512, 512, 0, stream>>>(qkv, kvtb, ln_w, ln_b, woutT, b_out, out);
}